// Round 6
// baseline (733.913 us; speedup 1.0000x reference)
//
#include <hip/hip_runtime.h>
#include <stdint.h>

#define TT 2048      // T
#define CC 2048      // C
#define NHEAD 16
#define HD 128
#define NB 4         // batch
#define MTOT (NB*TT) // 8192
#define KD 2048      // GEMM K (both projections)
#define NT 32        // K tiles of 64

typedef __attribute__((ext_vector_type(8))) short bf16x8;
typedef __attribute__((ext_vector_type(4))) float f32x4;

__device__ __forceinline__ unsigned short f2bf(float f) {
  unsigned u = __float_as_uint(f);
  u += 0x7FFF + ((u >> 16) & 1);
  return (unsigned short)(u >> 16);
}
__device__ __forceinline__ float bf2f(unsigned short h) {
  return __uint_as_float(((unsigned)h) << 16);
}

__device__ __forceinline__ void gl_lds16(const unsigned short* g, short* l) {
  __builtin_amdgcn_global_load_lds(
      (const __attribute__((address_space(1))) void*)(g),
      (__attribute__((address_space(3))) void*)(l), 16, 0, 0);
}

#define MFMA16(a, b, c) __builtin_amdgcn_mfma_f32_16x16x32_bf16((a), (b), (c), 0, 0, 0)

#define PRE_MFMA() do { \
  __builtin_amdgcn_s_barrier(); \
  asm volatile("s_waitcnt lgkmcnt(0)" ::: "memory"); \
  __builtin_amdgcn_s_setprio(1); \
} while(0)
#define POST_MFMA() do { \
  __builtin_amdgcn_s_setprio(0); \
  __builtin_amdgcn_s_barrier(); \
  __builtin_amdgcn_sched_barrier(0); \
} while(0)

// ---------------- fp32 -> bf16 cast ----------------
__global__ void k_f2b(const float* __restrict__ in, unsigned short* __restrict__ out, int n4) {
  int i = blockIdx.x * 256 + threadIdx.x;
  if (i >= n4) return;
  float4 v = reinterpret_cast<const float4*>(in)[i];
  ushort4 o;
  o.x = f2bf(v.x); o.y = f2bf(v.y); o.z = f2bf(v.z); o.w = f2bf(v.w);
  reinterpret_cast<ushort4*>(out)[i] = o;
}

// ---------------- RoPE table (fp64 on device; matches np ref closely) ----------------
__global__ void k_rope_tab(float* __restrict__ tab) {
  int t = blockIdx.x, i = threadIdx.x;  // 2048 x 64
  double inv = exp2(-(double)i * (13.287712379549449062 / 64.0)); // 10000^(-i/64)
  double ang = (double)t * inv;
  tab[(t*64 + i)*2 + 0] = (float)cos(ang);
  tab[(t*64 + i)*2 + 1] = (float)sin(ang);
}

// ================= 256x256 8-wave kk-split GEMM core (unchanged, round 4) =================
__device__ __forceinline__ void gemm256_core(
    const unsigned short* __restrict__ Ag,
    const unsigned short* __restrict__ Bg,
    int m0, int n0, short* lds, f32x4 (&acc)[8][4])
{
  const int tid = threadIdx.x;
  const int wid = tid >> 6, lane = tid & 63;
  const int wm = wid >> 2, wn = wid & 3;
  const int r15 = lane & 15, hi4 = lane >> 4;
  const int srow = wid*8 + (lane >> 3);
  const int schunk = (lane & 7) ^ (lane >> 3);

  const f32x4 fz = {0.f, 0.f, 0.f, 0.f};
#pragma unroll
  for (int i = 0; i < 8; i++)
#pragma unroll
    for (int j = 0; j < 4; j++) acc[i][j] = fz;

  int aoff0[8];
#pragma unroll
  for (int mi = 0; mi < 8; mi++) {
    int row = wm*128 + mi*16 + r15;
    aoff0[mi] = row*64 + ((hi4 ^ (row & 7))*8);
  }
  int boff0[4];
#pragma unroll
  for (int ni = 0; ni < 4; ni++) {
    int row = wn*64 + ni*16 + r15;
    boff0[ni] = row*64 + ((hi4 ^ (row & 7))*8);
  }

#define STAGE(G, L, GROW0, KT) do { \
    gl_lds16((G) + (size_t)((GROW0) + srow)*KD + (KT) + schunk*8, (L) + wid*512); \
    gl_lds16((G) + (size_t)((GROW0) + 64 + srow)*KD + (KT) + schunk*8, (L) + 4096 + wid*512); \
  } while(0)

  STAGE(Ag, lds,                        m0,       0);
  STAGE(Ag, lds + 8192,                 m0 + 128, 0);
  STAGE(Bg, lds + 32768,                n0,       0);
  STAGE(Bg, lds + 32768 + 8192,         n0 + 128, 0);
  STAGE(Bg, lds + 32768 + 16384,        n0,       64);
  STAGE(Bg, lds + 32768 + 16384 + 8192, n0 + 128, 64);
  asm volatile("s_waitcnt vmcnt(4)" ::: "memory");
  __builtin_amdgcn_s_barrier();
  __builtin_amdgcn_sched_barrier(0);

#pragma unroll 1
  for (int t = 0; t < NT; t++) {
    const int db = t & 1;
    short* Ab = lds + db*16384;
    short* Bb = lds + 32768 + db*16384;
    short* An = lds + (db ^ 1)*16384;
    const int kt = t*64;
    const bool stA = (t < NT - 1);
    const bool stB = (t < NT - 2);

    bf16x8 a[8], b[4][2];
    // ---- phase 0: kk=0 ----
#pragma unroll
    for (int mi = 0; mi < 8; mi++)
      a[mi] = *reinterpret_cast<const bf16x8*>(Ab + aoff0[mi]);
#pragma unroll
    for (int ni = 0; ni < 4; ni++) {
      b[ni][0] = *reinterpret_cast<const bf16x8*>(Bb + boff0[ni]);
      b[ni][1] = *reinterpret_cast<const bf16x8*>(Bb + (boff0[ni] ^ 32));
    }
    if (stA) {
      STAGE(Ag, An,        m0,       kt + 64);
      STAGE(Ag, An + 8192, m0 + 128, kt + 64);
    }
    PRE_MFMA();
#pragma unroll
    for (int mi = 0; mi < 8; mi++)
#pragma unroll
      for (int ni = 0; ni < 4; ni++)
        acc[mi][ni] = MFMA16(a[mi], b[ni][0], acc[mi][ni]);
    POST_MFMA();

    // ---- phase 1: kk=1 ----
#pragma unroll
    for (int mi = 0; mi < 8; mi++)
      a[mi] = *reinterpret_cast<const bf16x8*>(Ab + (aoff0[mi] ^ 32));
    if (stB) {
      STAGE(Bg, Bb,        n0,       kt + 128);
      STAGE(Bg, Bb + 8192, n0 + 128, kt + 128);
    }
    if (t >= NT - 2) asm volatile("s_waitcnt vmcnt(0)" ::: "memory");
    else             asm volatile("s_waitcnt vmcnt(4)" ::: "memory");
    PRE_MFMA();
#pragma unroll
    for (int mi = 0; mi < 8; mi++)
#pragma unroll
      for (int ni = 0; ni < 4; ni++)
        acc[mi][ni] = MFMA16(a[mi], b[ni][1], acc[mi][ni]);
    POST_MFMA();
  }
#undef STAGE
}

// ---------------- QKV projection + scatter (q,k -> [B,H,T,D]; v -> [B,H,D,T]) ----------------
__global__ __launch_bounds__(512, 2) void k_qkv(
    const unsigned short* __restrict__ xb,
    const unsigned short* __restrict__ wab,
    unsigned short* __restrict__ qr,
    unsigned short* __restrict__ kr,
    unsigned short* __restrict__ vt)
{
  __shared__ __align__(16) short lds[65536];
  f32x4 acc[8][4];
  int bid = blockIdx.x;                      // 768 blocks = 32 mt x 24 nt
  int swz = (bid & 7)*96 + (bid >> 3);       // bijective XCD swizzle (768 % 8 == 0)
  int m0 = (swz / 24)*256, n0 = (swz % 24)*256;
  gemm256_core(xb, wab, m0, n0, lds, acc);

  int tid = threadIdx.x, wid = tid >> 6, lane = tid & 63;
  int wm = wid >> 2, wn = wid & 3, r15 = lane & 15, hi4 = lane >> 4;
  int nw0 = n0 + wn*64;
  int which = nw0 >> 11;            // 0=q, 1=k, 2=v
  int h = (nw0 & 2047) >> 7;        // head (wave's 64 cols lie in one head)
#pragma unroll
  for (int mi = 0; mi < 8; mi++) {
    int m_base = m0 + wm*128 + mi*16 + hi4*4;
    int b = m_base >> 11;
    int t0 = m_base & (TT - 1);
#pragma unroll
    for (int ni = 0; ni < 4; ni++) {
      int d = (nw0 & 127) + ni*16 + r15;
      if (which == 2) {
        ushort4 pv;
        pv.x = f2bf(acc[mi][ni][0]); pv.y = f2bf(acc[mi][ni][1]);
        pv.z = f2bf(acc[mi][ni][2]); pv.w = f2bf(acc[mi][ni][3]);
        *reinterpret_cast<ushort4*>(vt + ((size_t)((b*NHEAD + h)*HD + d))*TT + t0) = pv;
      } else {
        unsigned short* dst = (which == 0) ? qr : kr;
        size_t base = ((size_t)(b*NHEAD + h)*TT + t0)*HD + d;
#pragma unroll
        for (int r = 0; r < 4; r++) dst[base + (size_t)r*HD] = f2bf(acc[mi][ni][r]);
      }
    }
  }
}

// ---------------- output projection ----------------
__global__ __launch_bounds__(512, 2) void k_proj(
    const unsigned short* __restrict__ yb,
    const unsigned short* __restrict__ wpb,
    float* __restrict__ out)
{
  __shared__ __align__(16) short lds[65536];
  f32x4 acc[8][4];
  int bid = blockIdx.x;                      // 256 blocks = 32 mt x 8 nt
  int swz = (bid & 7)*32 + (bid >> 3);
  int m0 = (swz / 8)*256, n0 = (swz % 8)*256;
  gemm256_core(yb, wpb, m0, n0, lds, acc);

  int tid = threadIdx.x, wid = tid >> 6, lane = tid & 63;
  int wm = wid >> 2, wn = wid & 3, r15 = lane & 15, hi4 = lane >> 4;
  int nw0 = n0 + wn*64;
#pragma unroll
  for (int mi = 0; mi < 8; mi++) {
    int m = m0 + wm*128 + mi*16 + hi4*4;
#pragma unroll
    for (int ni = 0; ni < 4; ni++) {
      int n = nw0 + ni*16 + r15;
#pragma unroll
      for (int r = 0; r < 4; r++)
        out[(size_t)(m + r)*CC + n] = acc[mi][ni][r];
    }
  }
}

// ---------------- in-place RoPE on q,k ----------------
__global__ void k_rope_apply(unsigned int* __restrict__ q32, unsigned int* __restrict__ k32,
                             const float* __restrict__ tab) {
  int i = blockIdx.x * 256 + threadIdx.x;   // over B*H*T*64
  int ii = i & 63;
  int t = (i >> 6) & (TT - 1);
  float c = tab[(t*64 + ii)*2], s = tab[(t*64 + ii)*2 + 1];
  unsigned qv = q32[i];
  float q1 = bf2f((unsigned short)qv), q2 = bf2f((unsigned short)(qv >> 16));
  unsigned short lo = f2bf(q1*c - q2*s), hi = f2bf(q1*s + q2*c);
  q32[i] = (unsigned)lo | ((unsigned)hi << 16);
  unsigned kv = k32[i];
  float k1 = bf2f((unsigned short)kv), k2 = bf2f((unsigned short)(kv >> 16));
  lo = f2bf(k1*c - k2*s); hi = f2bf(k1*s + k2*c);
  k32[i] = (unsigned)lo | ((unsigned)hi << 16);
}

// ---------------- causal flash attention, 2 q-subtiles/wave ----------------
// grid: 512 blocks = 64 (b*h) * 8 pairs of 128-row q-blocks (qb, 15-qb)
//       -> uniform 34 KV tiles/block; 2 blocks/CU resident (48KB LDS).
// 256 thr = 4 waves; wave w owns q rows [qb*128+w*16, +16) and [qb*128+64+w*16, +16).
// Shared-fragment MFMA: each K/V ds_read feeds 2 MFMA (both subtiles).
// T13 defer-max: skip O-rescale when max grows <= 8 (wave-uniform branch).
// T14 async-STAGE: next tile's K/V loaded to regs after QK^T, LDS-written post-barrier.
__global__ __launch_bounds__(256) void k_attn(
    const unsigned short* __restrict__ qr,
    const unsigned short* __restrict__ kr,
    const unsigned short* __restrict__ vt,
    unsigned short* __restrict__ yb)
{
  __shared__ short Ks[64*128];    // [kv][d], chunk-XOR swizzled
  __shared__ short Vs[128*64];    // [d][kv], chunk-XOR swizzled
  __shared__ short Pw[4*32*64];   // per-wave P (rows 0-15 sub0, 16-31 sub1), swizzled
  int bid = blockIdx.x;
  int bh = bid & 63, pr = bid >> 6;   // pr 0..7
  int tid = threadIdx.x, w = tid >> 6, lane = tid & 63;
  int r15 = lane & 15, hi4 = lane >> 4;
  const unsigned short* qg = qr + (size_t)bh*TT*HD;
  const unsigned short* kg = kr + (size_t)bh*TT*HD;
  const unsigned short* vg = vt + (size_t)bh*HD*TT;
  const f32x4 fz = {0.f,0.f,0.f,0.f};
  const float scale = 0.08838834764831845f; // 1/sqrt(128)
  int b = bh >> 4, h = bh & 15;

  // fixed per-thread staging geometry (same swizzle as reads)
  int kdst[4], vdst[4], ksoff[4];
  size_t vsoff[4];
#pragma unroll
  for (int i = 0; i < 4; i++) {
    int chunk = tid + i*256;
    int row = chunk >> 4, c16 = chunk & 15;
    kdst[i] = row*256 + ((c16 ^ (row & 7))*16);
    ksoff[i] = row*HD + c16*8;
    int d = chunk >> 3, c8 = chunk & 7;
    vdst[i] = d*128 + ((c8 ^ (d & 7))*16);
    vsoff[i] = (size_t)d*TT + c8*8;
  }

#pragma unroll 1
  for (int ph = 0; ph < 2; ph++) {
    int qb = ph ? (15 - pr) : pr;
    int qlo0 = qb*128 + w*16, qlo1 = qlo0 + 64;
    bf16x8 qf0[4], qf1[4];
    {
      int q0 = qlo0 + r15, q1 = qlo1 + r15;
#pragma unroll
      for (int kk = 0; kk < 4; kk++) {
        qf0[kk] = *reinterpret_cast<const bf16x8*>(qg + (size_t)q0*HD + kk*32 + hi4*8);
        qf1[kk] = *reinterpret_cast<const bf16x8*>(qg + (size_t)q1*HD + kk*32 + hi4*8);
      }
    }
    f32x4 ao0[8], ao1[8];
#pragma unroll
    for (int i = 0; i < 8; i++) { ao0[i] = fz; ao1[i] = fz; }
    float mrow0[4], lsum0[4], mrow1[4], lsum1[4];
#pragma unroll
    for (int r = 0; r < 4; r++) {
      mrow0[r] = -3.0e38f; lsum0[r] = 0.f;
      mrow1[r] = -3.0e38f; lsum1[r] = 0.f;
    }
    int ntiles = 2*qb + 2;
    uint4 st[8];

    // prologue: stage tile 0
#pragma unroll
    for (int i = 0; i < 4; i++) {
      st[i]     = *reinterpret_cast<const uint4*>(kg + ksoff[i]);
      st[4 + i] = *reinterpret_cast<const uint4*>(vg + vsoff[i]);
    }
    __syncthreads();   // previous phase's readers done
#pragma unroll
    for (int i = 0; i < 4; i++) {
      *reinterpret_cast<uint4*>((char*)Ks + kdst[i]) = st[i];
      *reinterpret_cast<uint4*>((char*)Vs + vdst[i]) = st[4 + i];
    }
    __syncthreads();

#pragma unroll 1
    for (int it = 0; it < ntiles; ++it) {
      int kv0 = it*64;
      bool more = (it + 1 < ntiles);
      // ---- QK^T both subtiles, shared K fragments ----
      f32x4 s0[4], s1[4];
#pragma unroll
      for (int n = 0; n < 4; n++) {
        s0[n] = fz; s1[n] = fz;
#pragma unroll
        for (int kk = 0; kk < 4; kk++) {
          int kvr = n*16 + r15;
          int ch = (kk*4 + hi4) ^ (kvr & 7);
          bf16x8 kf = *reinterpret_cast<const bf16x8*>((char*)Ks + kvr*256 + ch*16);
          s1[n] = MFMA16(qf1[kk], kf, s1[n]);
          s0[n] = MFMA16(qf0[kk], kf, s0[n]);
        }
      }
      // ---- T14: issue next tile's loads (regs) ----
      if (more) {
        int nkv = kv0 + 64;
#pragma unroll
        for (int i = 0; i < 4; i++) {
          st[i]     = *reinterpret_cast<const uint4*>(kg + (size_t)nkv*HD + ksoff[i]);
          st[4 + i] = *reinterpret_cast<const uint4*>(vg + vsoff[i] + nkv);
        }
      }
      // ---- softmax sub0 ----
      {
        float p[4][4], rmax[4];
#pragma unroll
        for (int r = 0; r < 4; r++) {
          int qgi = qlo0 + hi4*4 + r;
          float mx = -3.0e38f;
#pragma unroll
          for (int n = 0; n < 4; n++) {
            int kvg = kv0 + n*16 + r15;
            float sv = s0[n][r]*scale;
            sv = (kvg <= qgi) ? sv : -3.0e38f;
            p[n][r] = sv;
            mx = fmaxf(mx, sv);
          }
          rmax[r] = mx;
        }
#pragma unroll
        for (int mm = 1; mm < 16; mm <<= 1)
#pragma unroll
          for (int r = 0; r < 4; r++) rmax[r] = fmaxf(rmax[r], __shfl_xor(rmax[r], mm));
        bool ng = (rmax[0] <= mrow0[0] + 8.f) && (rmax[1] <= mrow0[1] + 8.f)
               && (rmax[2] <= mrow0[2] + 8.f) && (rmax[3] <= mrow0[3] + 8.f);
        bool defer = __all(ng);
        float alpha[4];
#pragma unroll
        for (int r = 0; r < 4; r++) {
          if (defer) { alpha[r] = 1.f; }
          else {
            float mnew = fmaxf(mrow0[r], rmax[r]);
            alpha[r] = __expf(mrow0[r] - mnew);
            mrow0[r] = mnew;
          }
        }
        float rsum[4];
#pragma unroll
        for (int r = 0; r < 4; r++) {
          float sum = 0.f;
#pragma unroll
          for (int n = 0; n < 4; n++) {
            float pv = __expf(p[n][r] - mrow0[r]);
            p[n][r] = pv; sum += pv;
          }
          rsum[r] = sum;
        }
#pragma unroll
        for (int mm = 1; mm < 16; mm <<= 1)
#pragma unroll
          for (int r = 0; r < 4; r++) rsum[r] += __shfl_xor(rsum[r], mm);
#pragma unroll
        for (int r = 0; r < 4; r++) lsum0[r] = lsum0[r]*alpha[r] + rsum[r];
        if (!defer) {
#pragma unroll
          for (int i = 0; i < 8; i++)
#pragma unroll
            for (int r = 0; r < 4; r++) ao0[i][r] *= alpha[r];
        }
#pragma unroll
        for (int r = 0; r < 4; r++) {
          int prow = hi4*4 + r;
#pragma unroll
          for (int n = 0; n < 4; n++) {
            int col = n*16 + r15;
            Pw[w*2048 + prow*64 + (col ^ ((prow & 7) << 3))] = (short)f2bf(p[n][r]);
          }
        }
      }
      // ---- softmax sub1 ----
      {
        float p[4][4], rmax[4];
#pragma unroll
        for (int r = 0; r < 4; r++) {
          int qgi = qlo1 + hi4*4 + r;
          float mx = -3.0e38f;
#pragma unroll
          for (int n = 0; n < 4; n++) {
            int kvg = kv0 + n*16 + r15;
            float sv = s1[n][r]*scale;
            sv = (kvg <= qgi) ? sv : -3.0e38f;
            p[n][r] = sv;
            mx = fmaxf(mx, sv);
          }
          rmax[r] = mx;
        }
#pragma unroll
        for (int mm = 1; mm < 16; mm <<= 1)
#pragma unroll
          for (int r = 0; r < 4; r++) rmax[r] = fmaxf(rmax[r], __shfl_xor(rmax[r], mm));
        bool ng = (rmax[0] <= mrow1[0] + 8.f) && (rmax[1] <= mrow1[1] + 8.f)
               && (rmax[2] <= mrow1[2] + 8.f) && (rmax[3] <= mrow1[3] + 8.f);
        bool defer = __all(ng);
        float alpha[4];
#pragma unroll
        for (int r = 0; r < 4; r++) {
          if (defer) { alpha[r] = 1.f; }
          else {
            float mnew = fmaxf(mrow1[r], rmax[r]);
            alpha[r] = __expf(mrow1[r] - mnew);
            mrow1[r] = mnew;
          }
        }
        float rsum[4];
#pragma unroll
        for (int r = 0; r < 4; r++) {
          float sum = 0.f;
#pragma unroll
          for (int n = 0; n < 4; n++) {
            float pv = __expf(p[n][r] - mrow1[r]);
            p[n][r] = pv; sum += pv;
          }
          rsum[r] = sum;
        }
#pragma unroll
        for (int mm = 1; mm < 16; mm <<= 1)
#pragma unroll
          for (int r = 0; r < 4; r++) rsum[r] += __shfl_xor(rsum[r], mm);
#pragma unroll
        for (int r = 0; r < 4; r++) lsum1[r] = lsum1[r]*alpha[r] + rsum[r];
        if (!defer) {
#pragma unroll
          for (int i = 0; i < 8; i++)
#pragma unroll
            for (int r = 0; r < 4; r++) ao1[i][r] *= alpha[r];
        }
#pragma unroll
        for (int r = 0; r < 4; r++) {
          int prow = 16 + hi4*4 + r;
#pragma unroll
          for (int n = 0; n < 4; n++) {
            int col = n*16 + r15;
            Pw[w*2048 + prow*64 + (col ^ ((prow & 7) << 3))] = (short)f2bf(p[n][r]);
          }
        }
      }
      // ---- PV both subtiles, shared V fragments ----
#pragma unroll
      for (int kk = 0; kk < 2; kk++) {
        int ch = (kk*4 + hi4) ^ (r15 & 7);
        bf16x8 pa0 = *reinterpret_cast<const bf16x8*>((char*)Pw + w*4096 + r15*128 + ch*16);
        bf16x8 pa1 = *reinterpret_cast<const bf16x8*>((char*)Pw + w*4096 + (16 + r15)*128 + ch*16);
#pragma unroll
        for (int ds_ = 0; ds_ < 8; ds_++) {
          int d = ds_*16 + r15;
          int vch = (kk*4 + hi4) ^ (d & 7);
          bf16x8 vf = *reinterpret_cast<const bf16x8*>((char*)Vs + d*128 + vch*16);
          ao1[ds_] = MFMA16(pa1, vf, ao1[ds_]);
          ao0[ds_] = MFMA16(pa0, vf, ao0[ds_]);
        }
      }
      // ---- T14 writeback: staged regs -> LDS ----
      if (more) {
        __syncthreads();
#pragma unroll
        for (int i = 0; i < 4; i++) {
          *reinterpret_cast<uint4*>((char*)Ks + kdst[i]) = st[i];
          *reinterpret_cast<uint4*>((char*)Vs + vdst[i]) = st[4 + i];
        }
        __syncthreads();
      }
    }
    // ---- epilogue both subtiles ----
#pragma unroll
    for (int r = 0; r < 4; r++) {
      int t0 = qlo0 + hi4*4 + r;
      int t1 = qlo1 + hi4*4 + r;
      float inv0 = 1.f / lsum0[r];
      float inv1 = 1.f / lsum1[r];
      size_t base0 = ((size_t)b*TT + t0)*CC + h*HD + r15;
      size_t base1 = ((size_t)b*TT + t1)*CC + h*HD + r15;
#pragma unroll
      for (int ds_ = 0; ds_ < 8; ds_++) {
        yb[base0 + ds_*16] = f2bf(ao0[ds_][r] * inv0);
        yb[base1 + ds_*16] = f2bf(ao1[ds_][r] * inv1);
      }
    }
  }
}

extern "C" void kernel_launch(void* const* d_in, const int* in_sizes, int n_in,
                              void* d_out, int out_size, void* d_ws, size_t ws_size,
                              hipStream_t stream) {
  const float* x  = (const float*)d_in[0];
  const float* wa = (const float*)d_in[1];
  const float* wp = (const float*)d_in[2];
  float* out = (float*)d_out;
  char* ws = (char*)d_ws;
  size_t off = 0;
  unsigned short* xb  = (unsigned short*)(ws + off); off += (size_t)MTOT*CC*2;
  unsigned short* wab = (unsigned short*)(ws + off); off += (size_t)3*CC*CC*2;
  unsigned short* wpb = (unsigned short*)(ws + off); off += (size_t)CC*CC*2;
  unsigned short* qr  = (unsigned short*)(ws + off); off += (size_t)MTOT*CC*2;
  unsigned short* kr  = (unsigned short*)(ws + off); off += (size_t)MTOT*CC*2;
  unsigned short* vt  = (unsigned short*)(ws + off); off += (size_t)MTOT*CC*2;
  unsigned short* yb  = (unsigned short*)(ws + off); off += (size_t)MTOT*CC*2;
  float* tab          = (float*)(ws + off);          off += (size_t)TT*64*2*4;

  k_f2b<<<dim3(16384), dim3(256), 0, stream>>>(x,  xb,  MTOT*CC/4);
  k_f2b<<<dim3(12288), dim3(256), 0, stream>>>(wa, wab, 3*CC*CC/4);
  k_f2b<<<dim3(4096),  dim3(256), 0, stream>>>(wp, wpb, CC*CC/4);
  k_rope_tab<<<dim3(TT), dim3(64), 0, stream>>>(tab);
  k_qkv<<<dim3(768), dim3(512), 0, stream>>>(xb, wab, qr, kr, vt);
  k_rope_apply<<<dim3(32768), dim3(256), 0, stream>>>((unsigned int*)qr, (unsigned int*)kr, tab);
  k_attn<<<dim3(512), dim3(256), 0, stream>>>(qr, kr, vt, yb);
  k_proj<<<dim3(256), dim3(512), 0, stream>>>(yb, wpb, out);
}

// Round 7
// 566.468 us; speedup vs baseline: 1.2956x; 1.2956x over previous
//
#include <hip/hip_runtime.h>
#include <stdint.h>

#define TT 2048      // T
#define CC 2048      // C
#define NHEAD 16
#define HD 128
#define NB 4         // batch
#define MTOT (NB*TT) // 8192
#define KD 2048      // GEMM K (both projections)
#define NT 32        // K tiles of 64

typedef __attribute__((ext_vector_type(8))) short bf16x8;
typedef __attribute__((ext_vector_type(4))) float f32x4;

__device__ __forceinline__ unsigned short f2bf(float f) {
  unsigned u = __float_as_uint(f);
  u += 0x7FFF + ((u >> 16) & 1);
  return (unsigned short)(u >> 16);
}
__device__ __forceinline__ float bf2f(unsigned short h) {
  return __uint_as_float(((unsigned)h) << 16);
}

__device__ __forceinline__ void gl_lds16(const unsigned short* g, short* l) {
  __builtin_amdgcn_global_load_lds(
      (const __attribute__((address_space(1))) void*)(g),
      (__attribute__((address_space(3))) void*)(l), 16, 0, 0);
}

#define MFMA16(a, b, c) __builtin_amdgcn_mfma_f32_16x16x32_bf16((a), (b), (c), 0, 0, 0)

#define PRE_MFMA() do { \
  __builtin_amdgcn_s_barrier(); \
  asm volatile("s_waitcnt lgkmcnt(0)" ::: "memory"); \
  __builtin_amdgcn_s_setprio(1); \
} while(0)
#define POST_MFMA() do { \
  __builtin_amdgcn_s_setprio(0); \
  __builtin_amdgcn_s_barrier(); \
  __builtin_amdgcn_sched_barrier(0); \
} while(0)

// ---------------- fp32 -> bf16 cast ----------------
__global__ void k_f2b(const float* __restrict__ in, unsigned short* __restrict__ out, int n4) {
  int i = blockIdx.x * 256 + threadIdx.x;
  if (i >= n4) return;
  float4 v = reinterpret_cast<const float4*>(in)[i];
  ushort4 o;
  o.x = f2bf(v.x); o.y = f2bf(v.y); o.z = f2bf(v.z); o.w = f2bf(v.w);
  reinterpret_cast<ushort4*>(out)[i] = o;
}

// ---------------- RoPE table (fp64 on device; matches np ref closely) ----------------
__global__ void k_rope_tab(float* __restrict__ tab) {
  int t = blockIdx.x, i = threadIdx.x;  // 2048 x 64
  double inv = exp2(-(double)i * (13.287712379549449062 / 64.0)); // 10000^(-i/64)
  double ang = (double)t * inv;
  tab[(t*64 + i)*2 + 0] = (float)cos(ang);
  tab[(t*64 + i)*2 + 1] = (float)sin(ang);
}

// ================= 256x256 8-wave kk-split GEMM core (unchanged, round 4) =================
__device__ __forceinline__ void gemm256_core(
    const unsigned short* __restrict__ Ag,
    const unsigned short* __restrict__ Bg,
    int m0, int n0, short* lds, f32x4 (&acc)[8][4])
{
  const int tid = threadIdx.x;
  const int wid = tid >> 6, lane = tid & 63;
  const int wm = wid >> 2, wn = wid & 3;
  const int r15 = lane & 15, hi4 = lane >> 4;
  const int srow = wid*8 + (lane >> 3);
  const int schunk = (lane & 7) ^ (lane >> 3);

  const f32x4 fz = {0.f, 0.f, 0.f, 0.f};
#pragma unroll
  for (int i = 0; i < 8; i++)
#pragma unroll
    for (int j = 0; j < 4; j++) acc[i][j] = fz;

  int aoff0[8];
#pragma unroll
  for (int mi = 0; mi < 8; mi++) {
    int row = wm*128 + mi*16 + r15;
    aoff0[mi] = row*64 + ((hi4 ^ (row & 7))*8);
  }
  int boff0[4];
#pragma unroll
  for (int ni = 0; ni < 4; ni++) {
    int row = wn*64 + ni*16 + r15;
    boff0[ni] = row*64 + ((hi4 ^ (row & 7))*8);
  }

#define STAGE(G, L, GROW0, KT) do { \
    gl_lds16((G) + (size_t)((GROW0) + srow)*KD + (KT) + schunk*8, (L) + wid*512); \
    gl_lds16((G) + (size_t)((GROW0) + 64 + srow)*KD + (KT) + schunk*8, (L) + 4096 + wid*512); \
  } while(0)

  STAGE(Ag, lds,                        m0,       0);
  STAGE(Ag, lds + 8192,                 m0 + 128, 0);
  STAGE(Bg, lds + 32768,                n0,       0);
  STAGE(Bg, lds + 32768 + 8192,         n0 + 128, 0);
  STAGE(Bg, lds + 32768 + 16384,        n0,       64);
  STAGE(Bg, lds + 32768 + 16384 + 8192, n0 + 128, 64);
  asm volatile("s_waitcnt vmcnt(4)" ::: "memory");
  __builtin_amdgcn_s_barrier();
  __builtin_amdgcn_sched_barrier(0);

#pragma unroll 1
  for (int t = 0; t < NT; t++) {
    const int db = t & 1;
    short* Ab = lds + db*16384;
    short* Bb = lds + 32768 + db*16384;
    short* An = lds + (db ^ 1)*16384;
    const int kt = t*64;
    const bool stA = (t < NT - 1);
    const bool stB = (t < NT - 2);

    bf16x8 a[8], b[4][2];
    // ---- phase 0: kk=0 ----
#pragma unroll
    for (int mi = 0; mi < 8; mi++)
      a[mi] = *reinterpret_cast<const bf16x8*>(Ab + aoff0[mi]);
#pragma unroll
    for (int ni = 0; ni < 4; ni++) {
      b[ni][0] = *reinterpret_cast<const bf16x8*>(Bb + boff0[ni]);
      b[ni][1] = *reinterpret_cast<const bf16x8*>(Bb + (boff0[ni] ^ 32));
    }
    if (stA) {
      STAGE(Ag, An,        m0,       kt + 64);
      STAGE(Ag, An + 8192, m0 + 128, kt + 64);
    }
    PRE_MFMA();
#pragma unroll
    for (int mi = 0; mi < 8; mi++)
#pragma unroll
      for (int ni = 0; ni < 4; ni++)
        acc[mi][ni] = MFMA16(a[mi], b[ni][0], acc[mi][ni]);
    POST_MFMA();

    // ---- phase 1: kk=1 ----
#pragma unroll
    for (int mi = 0; mi < 8; mi++)
      a[mi] = *reinterpret_cast<const bf16x8*>(Ab + (aoff0[mi] ^ 32));
    if (stB) {
      STAGE(Bg, Bb,        n0,       kt + 128);
      STAGE(Bg, Bb + 8192, n0 + 128, kt + 128);
    }
    if (t >= NT - 2) asm volatile("s_waitcnt vmcnt(0)" ::: "memory");
    else             asm volatile("s_waitcnt vmcnt(4)" ::: "memory");
    PRE_MFMA();
#pragma unroll
    for (int mi = 0; mi < 8; mi++)
#pragma unroll
      for (int ni = 0; ni < 4; ni++)
        acc[mi][ni] = MFMA16(a[mi], b[ni][1], acc[mi][ni]);
    POST_MFMA();
  }
#undef STAGE
}

// ---------------- QKV projection + scatter (q,k -> [B,H,T,D]; v -> [B,H,D,T]) ----------------
__global__ __launch_bounds__(512, 2) void k_qkv(
    const unsigned short* __restrict__ xb,
    const unsigned short* __restrict__ wab,
    unsigned short* __restrict__ qr,
    unsigned short* __restrict__ kr,
    unsigned short* __restrict__ vt)
{
  __shared__ __align__(16) short lds[65536];
  f32x4 acc[8][4];
  int bid = blockIdx.x;                      // 768 blocks = 32 mt x 24 nt
  int swz = (bid & 7)*96 + (bid >> 3);       // bijective XCD swizzle (768 % 8 == 0)
  int m0 = (swz / 24)*256, n0 = (swz % 24)*256;
  gemm256_core(xb, wab, m0, n0, lds, acc);

  int tid = threadIdx.x, wid = tid >> 6, lane = tid & 63;
  int wm = wid >> 2, wn = wid & 3, r15 = lane & 15, hi4 = lane >> 4;
  int nw0 = n0 + wn*64;
  int which = nw0 >> 11;            // 0=q, 1=k, 2=v
  int h = (nw0 & 2047) >> 7;        // head (wave's 64 cols lie in one head)
#pragma unroll
  for (int mi = 0; mi < 8; mi++) {
    int m_base = m0 + wm*128 + mi*16 + hi4*4;
    int b = m_base >> 11;
    int t0 = m_base & (TT - 1);
#pragma unroll
    for (int ni = 0; ni < 4; ni++) {
      int d = (nw0 & 127) + ni*16 + r15;
      if (which == 2) {
        ushort4 pv;
        pv.x = f2bf(acc[mi][ni][0]); pv.y = f2bf(acc[mi][ni][1]);
        pv.z = f2bf(acc[mi][ni][2]); pv.w = f2bf(acc[mi][ni][3]);
        *reinterpret_cast<ushort4*>(vt + ((size_t)((b*NHEAD + h)*HD + d))*TT + t0) = pv;
      } else {
        unsigned short* dst = (which == 0) ? qr : kr;
        size_t base = ((size_t)(b*NHEAD + h)*TT + t0)*HD + d;
#pragma unroll
        for (int r = 0; r < 4; r++) dst[base + (size_t)r*HD] = f2bf(acc[mi][ni][r]);
      }
    }
  }
}

// ---------------- output projection ----------------
__global__ __launch_bounds__(512, 2) void k_proj(
    const unsigned short* __restrict__ yb,
    const unsigned short* __restrict__ wpb,
    float* __restrict__ out)
{
  __shared__ __align__(16) short lds[65536];
  f32x4 acc[8][4];
  int bid = blockIdx.x;                      // 256 blocks = 32 mt x 8 nt
  int swz = (bid & 7)*32 + (bid >> 3);
  int m0 = (swz / 8)*256, n0 = (swz % 8)*256;
  gemm256_core(yb, wpb, m0, n0, lds, acc);

  int tid = threadIdx.x, wid = tid >> 6, lane = tid & 63;
  int wm = wid >> 2, wn = wid & 3, r15 = lane & 15, hi4 = lane >> 4;
  int nw0 = n0 + wn*64;
#pragma unroll
  for (int mi = 0; mi < 8; mi++) {
    int m = m0 + wm*128 + mi*16 + hi4*4;
#pragma unroll
    for (int ni = 0; ni < 4; ni++) {
      int n = nw0 + ni*16 + r15;
#pragma unroll
      for (int r = 0; r < 4; r++)
        out[(size_t)(m + r)*CC + n] = acc[mi][ni][r];
    }
  }
}

// ---------------- in-place RoPE on q,k ----------------
__global__ void k_rope_apply(unsigned int* __restrict__ q32, unsigned int* __restrict__ k32,
                             const float* __restrict__ tab) {
  int i = blockIdx.x * 256 + threadIdx.x;   // over B*H*T*64
  int ii = i & 63;
  int t = (i >> 6) & (TT - 1);
  float c = tab[(t*64 + ii)*2], s = tab[(t*64 + ii)*2 + 1];
  unsigned qv = q32[i];
  float q1 = bf2f((unsigned short)qv), q2 = bf2f((unsigned short)(qv >> 16));
  unsigned short lo = f2bf(q1*c - q2*s), hi = f2bf(q1*s + q2*c);
  q32[i] = (unsigned)lo | ((unsigned)hi << 16);
  unsigned kv = k32[i];
  float k1 = bf2f((unsigned short)kv), k2 = bf2f((unsigned short)(kv >> 16));
  lo = f2bf(k1*c - k2*s); hi = f2bf(k1*s + k2*c);
  k32[i] = (unsigned)lo | ((unsigned)hi << 16);
}

// ---------------- causal flash attention, 2 q-subtiles/wave ----------------
// grid: 512 blocks = 64 (b*h) * 8 pairs of 128-row q-blocks (qb, 15-qb)
//       -> uniform 34 KV tiles/block; 2 blocks/CU resident (48KB LDS).
// __launch_bounds__(256, 2): 2 waves/EU target -> VGPR budget 256 (round-6 fix:
// bare (256) budgeted ~172 and spilled ~1KB/thread -> 130MB scratch writes).
__global__ __launch_bounds__(256, 2) void k_attn(
    const unsigned short* __restrict__ qr,
    const unsigned short* __restrict__ kr,
    const unsigned short* __restrict__ vt,
    unsigned short* __restrict__ yb)
{
  __shared__ short Ks[64*128];    // [kv][d], chunk-XOR swizzled
  __shared__ short Vs[128*64];    // [d][kv], chunk-XOR swizzled
  __shared__ short Pw[4*32*64];   // per-wave P (rows 0-15 sub0, 16-31 sub1), swizzled
  int bid = blockIdx.x;
  int bh = bid & 63, pr = bid >> 6;   // pr 0..7
  int tid = threadIdx.x, w = tid >> 6, lane = tid & 63;
  int r15 = lane & 15, hi4 = lane >> 4;
  const unsigned short* qg = qr + (size_t)bh*TT*HD;
  const unsigned short* kg = kr + (size_t)bh*TT*HD;
  const unsigned short* vg = vt + (size_t)bh*HD*TT;
  const f32x4 fz = {0.f,0.f,0.f,0.f};
  const float scale = 0.08838834764831845f; // 1/sqrt(128)
  int b = bh >> 4, h = bh & 15;

  // fixed per-thread staging geometry (same swizzle as reads)
  int kdst[4], vdst[4], ksoff[4];
  size_t vsoff[4];
#pragma unroll
  for (int i = 0; i < 4; i++) {
    int chunk = tid + i*256;
    int row = chunk >> 4, c16 = chunk & 15;
    kdst[i] = row*256 + ((c16 ^ (row & 7))*16);
    ksoff[i] = row*HD + c16*8;
    int d = chunk >> 3, c8 = chunk & 7;
    vdst[i] = d*128 + ((c8 ^ (d & 7))*16);
    vsoff[i] = (size_t)d*TT + c8*8;
  }

#pragma unroll 1
  for (int ph = 0; ph < 2; ph++) {
    int qb = ph ? (15 - pr) : pr;
    int qlo0 = qb*128 + w*16, qlo1 = qlo0 + 64;
    bf16x8 qf0[4], qf1[4];
    {
      int q0 = qlo0 + r15, q1 = qlo1 + r15;
#pragma unroll
      for (int kk = 0; kk < 4; kk++) {
        qf0[kk] = *reinterpret_cast<const bf16x8*>(qg + (size_t)q0*HD + kk*32 + hi4*8);
        qf1[kk] = *reinterpret_cast<const bf16x8*>(qg + (size_t)q1*HD + kk*32 + hi4*8);
      }
    }
    f32x4 ao0[8], ao1[8];
#pragma unroll
    for (int i = 0; i < 8; i++) { ao0[i] = fz; ao1[i] = fz; }
    float mrow0[4], lsum0[4], mrow1[4], lsum1[4];
#pragma unroll
    for (int r = 0; r < 4; r++) {
      mrow0[r] = -3.0e38f; lsum0[r] = 0.f;
      mrow1[r] = -3.0e38f; lsum1[r] = 0.f;
    }
    int ntiles = 2*qb + 2;
    uint4 st[8];

    // prologue: stage tile 0
#pragma unroll
    for (int i = 0; i < 4; i++) {
      st[i]     = *reinterpret_cast<const uint4*>(kg + ksoff[i]);
      st[4 + i] = *reinterpret_cast<const uint4*>(vg + vsoff[i]);
    }
    __syncthreads();   // previous phase's readers done
#pragma unroll
    for (int i = 0; i < 4; i++) {
      *reinterpret_cast<uint4*>((char*)Ks + kdst[i]) = st[i];
      *reinterpret_cast<uint4*>((char*)Vs + vdst[i]) = st[4 + i];
    }
    __syncthreads();

#pragma unroll 1
    for (int it = 0; it < ntiles; ++it) {
      int kv0 = it*64;
      bool more = (it + 1 < ntiles);
      // ---- QK^T both subtiles, shared K fragments ----
      f32x4 s0[4], s1[4];
      __builtin_amdgcn_s_setprio(1);
#pragma unroll
      for (int n = 0; n < 4; n++) {
        s0[n] = fz; s1[n] = fz;
#pragma unroll
        for (int kk = 0; kk < 4; kk++) {
          int kvr = n*16 + r15;
          int ch = (kk*4 + hi4) ^ (kvr & 7);
          bf16x8 kf = *reinterpret_cast<const bf16x8*>((char*)Ks + kvr*256 + ch*16);
          s1[n] = MFMA16(qf1[kk], kf, s1[n]);
          s0[n] = MFMA16(qf0[kk], kf, s0[n]);
        }
      }
      __builtin_amdgcn_s_setprio(0);
      // ---- T14: issue next tile's loads (regs) ----
      if (more) {
        int nkv = kv0 + 64;
#pragma unroll
        for (int i = 0; i < 4; i++) {
          st[i]     = *reinterpret_cast<const uint4*>(kg + (size_t)nkv*HD + ksoff[i]);
          st[4 + i] = *reinterpret_cast<const uint4*>(vg + vsoff[i] + nkv);
        }
      }
      // ---- softmax sub0 ----
      {
        float p[4][4], rmax[4];
#pragma unroll
        for (int r = 0; r < 4; r++) {
          int qgi = qlo0 + hi4*4 + r;
          float mx = -3.0e38f;
#pragma unroll
          for (int n = 0; n < 4; n++) {
            int kvg = kv0 + n*16 + r15;
            float sv = s0[n][r]*scale;
            sv = (kvg <= qgi) ? sv : -3.0e38f;
            p[n][r] = sv;
            mx = fmaxf(mx, sv);
          }
          rmax[r] = mx;
        }
#pragma unroll
        for (int mm = 1; mm < 16; mm <<= 1)
#pragma unroll
          for (int r = 0; r < 4; r++) rmax[r] = fmaxf(rmax[r], __shfl_xor(rmax[r], mm));
        bool ng = (rmax[0] <= mrow0[0] + 8.f) && (rmax[1] <= mrow0[1] + 8.f)
               && (rmax[2] <= mrow0[2] + 8.f) && (rmax[3] <= mrow0[3] + 8.f);
        bool defer = __all(ng);
        float alpha[4];
#pragma unroll
        for (int r = 0; r < 4; r++) {
          if (defer) { alpha[r] = 1.f; }
          else {
            float mnew = fmaxf(mrow0[r], rmax[r]);
            alpha[r] = __expf(mrow0[r] - mnew);
            mrow0[r] = mnew;
          }
        }
        float rsum[4];
#pragma unroll
        for (int r = 0; r < 4; r++) {
          float sum = 0.f;
#pragma unroll
          for (int n = 0; n < 4; n++) {
            float pv = __expf(p[n][r] - mrow0[r]);
            p[n][r] = pv; sum += pv;
          }
          rsum[r] = sum;
        }
#pragma unroll
        for (int mm = 1; mm < 16; mm <<= 1)
#pragma unroll
          for (int r = 0; r < 4; r++) rsum[r] += __shfl_xor(rsum[r], mm);
#pragma unroll
        for (int r = 0; r < 4; r++) lsum0[r] = lsum0[r]*alpha[r] + rsum[r];
        if (!defer) {
#pragma unroll
          for (int i = 0; i < 8; i++)
#pragma unroll
            for (int r = 0; r < 4; r++) ao0[i][r] *= alpha[r];
        }
#pragma unroll
        for (int r = 0; r < 4; r++) {
          int prow = hi4*4 + r;
#pragma unroll
          for (int n = 0; n < 4; n++) {
            int col = n*16 + r15;
            Pw[w*2048 + prow*64 + (col ^ ((prow & 7) << 3))] = (short)f2bf(p[n][r]);
          }
        }
      }
      // ---- softmax sub1 ----
      {
        float p[4][4], rmax[4];
#pragma unroll
        for (int r = 0; r < 4; r++) {
          int qgi = qlo1 + hi4*4 + r;
          float mx = -3.0e38f;
#pragma unroll
          for (int n = 0; n < 4; n++) {
            int kvg = kv0 + n*16 + r15;
            float sv = s1[n][r]*scale;
            sv = (kvg <= qgi) ? sv : -3.0e38f;
            p[n][r] = sv;
            mx = fmaxf(mx, sv);
          }
          rmax[r] = mx;
        }
#pragma unroll
        for (int mm = 1; mm < 16; mm <<= 1)
#pragma unroll
          for (int r = 0; r < 4; r++) rmax[r] = fmaxf(rmax[r], __shfl_xor(rmax[r], mm));
        bool ng = (rmax[0] <= mrow1[0] + 8.f) && (rmax[1] <= mrow1[1] + 8.f)
               && (rmax[2] <= mrow1[2] + 8.f) && (rmax[3] <= mrow1[3] + 8.f);
        bool defer = __all(ng);
        float alpha[4];
#pragma unroll
        for (int r = 0; r < 4; r++) {
          if (defer) { alpha[r] = 1.f; }
          else {
            float mnew = fmaxf(mrow1[r], rmax[r]);
            alpha[r] = __expf(mrow1[r] - mnew);
            mrow1[r] = mnew;
          }
        }
        float rsum[4];
#pragma unroll
        for (int r = 0; r < 4; r++) {
          float sum = 0.f;
#pragma unroll
          for (int n = 0; n < 4; n++) {
            float pv = __expf(p[n][r] - mrow1[r]);
            p[n][r] = pv; sum += pv;
          }
          rsum[r] = sum;
        }
#pragma unroll
        for (int mm = 1; mm < 16; mm <<= 1)
#pragma unroll
          for (int r = 0; r < 4; r++) rsum[r] += __shfl_xor(rsum[r], mm);
#pragma unroll
        for (int r = 0; r < 4; r++) lsum1[r] = lsum1[r]*alpha[r] + rsum[r];
        if (!defer) {
#pragma unroll
          for (int i = 0; i < 8; i++)
#pragma unroll
            for (int r = 0; r < 4; r++) ao1[i][r] *= alpha[r];
        }
#pragma unroll
        for (int r = 0; r < 4; r++) {
          int prow = 16 + hi4*4 + r;
#pragma unroll
          for (int n = 0; n < 4; n++) {
            int col = n*16 + r15;
            Pw[w*2048 + prow*64 + (col ^ ((prow & 7) << 3))] = (short)f2bf(p[n][r]);
          }
        }
      }
      // ---- PV both subtiles, shared V fragments ----
      __builtin_amdgcn_s_setprio(1);
#pragma unroll
      for (int kk = 0; kk < 2; kk++) {
        int ch = (kk*4 + hi4) ^ (r15 & 7);
        bf16x8 pa0 = *reinterpret_cast<const bf16x8*>((char*)Pw + w*4096 + r15*128 + ch*16);
        bf16x8 pa1 = *reinterpret_cast<const bf16x8*>((char*)Pw + w*4096 + (16 + r15)*128 + ch*16);
#pragma unroll
        for (int ds_ = 0; ds_ < 8; ds_++) {
          int d = ds_*16 + r15;
          int vch = (kk*4 + hi4) ^ (d & 7);
          bf16x8 vf = *reinterpret_cast<const bf16x8*>((char*)Vs + d*128 + vch*16);
          ao1[ds_] = MFMA16(pa1, vf, ao1[ds_]);
          ao0[ds_] = MFMA16(pa0, vf, ao0[ds_]);
        }
      }
      __builtin_amdgcn_s_setprio(0);
      // ---- T14 writeback: staged regs -> LDS ----
      if (more) {
        __syncthreads();
#pragma unroll
        for (int i = 0; i < 4; i++) {
          *reinterpret_cast<uint4*>((char*)Ks + kdst[i]) = st[i];
          *reinterpret_cast<uint4*>((char*)Vs + vdst[i]) = st[4 + i];
        }
        __syncthreads();
      }
    }
    // ---- epilogue both subtiles ----
#pragma unroll
    for (int r = 0; r < 4; r++) {
      int t0 = qlo0 + hi4*4 + r;
      int t1 = qlo1 + hi4*4 + r;
      float inv0 = 1.f / lsum0[r];
      float inv1 = 1.f / lsum1[r];
      size_t base0 = ((size_t)b*TT + t0)*CC + h*HD + r15;
      size_t base1 = ((size_t)b*TT + t1)*CC + h*HD + r15;
#pragma unroll
      for (int ds_ = 0; ds_ < 8; ds_++) {
        yb[base0 + ds_*16] = f2bf(ao0[ds_][r] * inv0);
        yb[base1 + ds_*16] = f2bf(ao1[ds_][r] * inv1);
      }
    }
  }
}

extern "C" void kernel_launch(void* const* d_in, const int* in_sizes, int n_in,
                              void* d_out, int out_size, void* d_ws, size_t ws_size,
                              hipStream_t stream) {
  const float* x  = (const float*)d_in[0];
  const float* wa = (const float*)d_in[1];
  const float* wp = (const float*)d_in[2];
  float* out = (float*)d_out;
  char* ws = (char*)d_ws;
  size_t off = 0;
  unsigned short* xb  = (unsigned short*)(ws + off); off += (size_t)MTOT*CC*2;
  unsigned short* wab = (unsigned short*)(ws + off); off += (size_t)3*CC*CC*2;
  unsigned short* wpb = (unsigned short*)(ws + off); off += (size_t)CC*CC*2;
  unsigned short* qr  = (unsigned short*)(ws + off); off += (size_t)MTOT*CC*2;
  unsigned short* kr  = (unsigned short*)(ws + off); off += (size_t)MTOT*CC*2;
  unsigned short* vt  = (unsigned short*)(ws + off); off += (size_t)MTOT*CC*2;
  unsigned short* yb  = (unsigned short*)(ws + off); off += (size_t)MTOT*CC*2;
  float* tab          = (float*)(ws + off);          off += (size_t)TT*64*2*4;

  k_f2b<<<dim3(16384), dim3(256), 0, stream>>>(x,  xb,  MTOT*CC/4);
  k_f2b<<<dim3(12288), dim3(256), 0, stream>>>(wa, wab, 3*CC*CC/4);
  k_f2b<<<dim3(4096),  dim3(256), 0, stream>>>(wp, wpb, CC*CC/4);
  k_rope_tab<<<dim3(TT), dim3(64), 0, stream>>>(tab);
  k_qkv<<<dim3(768), dim3(512), 0, stream>>>(xb, wab, qr, kr, vt);
  k_rope_apply<<<dim3(32768), dim3(256), 0, stream>>>((unsigned int*)qr, (unsigned int*)kr, tab);
  k_attn<<<dim3(512), dim3(256), 0, stream>>>(qr, kr, vt, yb);
  k_proj<<<dim3(256), dim3(512), 0, stream>>>(yb, wpb, out);
}

// Round 8
// 553.730 us; speedup vs baseline: 1.3254x; 1.0230x over previous
//
#include <hip/hip_runtime.h>
#include <stdint.h>

#define TT 2048      // T
#define CC 2048      // C
#define NHEAD 16
#define HD 128
#define NB 4         // batch
#define MTOT (NB*TT) // 8192
#define KD 2048      // GEMM K (both projections)
#define NT 32        // K tiles of 64

typedef __attribute__((ext_vector_type(8))) short bf16x8;
typedef __attribute__((ext_vector_type(4))) float f32x4;

__device__ __forceinline__ unsigned short f2bf(float f) {
  unsigned u = __float_as_uint(f);
  u += 0x7FFF + ((u >> 16) & 1);
  return (unsigned short)(u >> 16);
}
__device__ __forceinline__ float bf2f(unsigned short h) {
  return __uint_as_float(((unsigned)h) << 16);
}

__device__ __forceinline__ void gl_lds16(const unsigned short* g, short* l) {
  __builtin_amdgcn_global_load_lds(
      (const __attribute__((address_space(1))) void*)(g),
      (__attribute__((address_space(3))) void*)(l), 16, 0, 0);
}

#define MFMA16(a, b, c) __builtin_amdgcn_mfma_f32_16x16x32_bf16((a), (b), (c), 0, 0, 0)

#define PRE_MFMA() do { \
  __builtin_amdgcn_s_barrier(); \
  asm volatile("s_waitcnt lgkmcnt(0)" ::: "memory"); \
  __builtin_amdgcn_s_setprio(1); \
} while(0)
#define POST_MFMA() do { \
  __builtin_amdgcn_s_setprio(0); \
  __builtin_amdgcn_s_barrier(); \
  __builtin_amdgcn_sched_barrier(0); \
} while(0)

// ---------------- fp32 -> bf16 cast ----------------
__global__ void k_f2b(const float* __restrict__ in, unsigned short* __restrict__ out, int n4) {
  int i = blockIdx.x * 256 + threadIdx.x;
  if (i >= n4) return;
  float4 v = reinterpret_cast<const float4*>(in)[i];
  ushort4 o;
  o.x = f2bf(v.x); o.y = f2bf(v.y); o.z = f2bf(v.z); o.w = f2bf(v.w);
  reinterpret_cast<ushort4*>(out)[i] = o;
}

// ---------------- RoPE table (fp64 on device; matches np ref closely) ----------------
__global__ void k_rope_tab(float* __restrict__ tab) {
  int t = blockIdx.x, i = threadIdx.x;  // 2048 x 64
  double inv = exp2(-(double)i * (13.287712379549449062 / 64.0)); // 10000^(-i/64)
  double ang = (double)t * inv;
  tab[(t*64 + i)*2 + 0] = (float)cos(ang);
  tab[(t*64 + i)*2 + 1] = (float)sin(ang);
}

// ================= 256x256 8-wave kk-split GEMM core (unchanged, round 4) =================
__device__ __forceinline__ void gemm256_core(
    const unsigned short* __restrict__ Ag,
    const unsigned short* __restrict__ Bg,
    int m0, int n0, short* lds, f32x4 (&acc)[8][4])
{
  const int tid = threadIdx.x;
  const int wid = tid >> 6, lane = tid & 63;
  const int wm = wid >> 2, wn = wid & 3;
  const int r15 = lane & 15, hi4 = lane >> 4;
  const int srow = wid*8 + (lane >> 3);
  const int schunk = (lane & 7) ^ (lane >> 3);

  const f32x4 fz = {0.f, 0.f, 0.f, 0.f};
#pragma unroll
  for (int i = 0; i < 8; i++)
#pragma unroll
    for (int j = 0; j < 4; j++) acc[i][j] = fz;

  int aoff0[8];
#pragma unroll
  for (int mi = 0; mi < 8; mi++) {
    int row = wm*128 + mi*16 + r15;
    aoff0[mi] = row*64 + ((hi4 ^ (row & 7))*8);
  }
  int boff0[4];
#pragma unroll
  for (int ni = 0; ni < 4; ni++) {
    int row = wn*64 + ni*16 + r15;
    boff0[ni] = row*64 + ((hi4 ^ (row & 7))*8);
  }

#define STAGE(G, L, GROW0, KT) do { \
    gl_lds16((G) + (size_t)((GROW0) + srow)*KD + (KT) + schunk*8, (L) + wid*512); \
    gl_lds16((G) + (size_t)((GROW0) + 64 + srow)*KD + (KT) + schunk*8, (L) + 4096 + wid*512); \
  } while(0)

  STAGE(Ag, lds,                        m0,       0);
  STAGE(Ag, lds + 8192,                 m0 + 128, 0);
  STAGE(Bg, lds + 32768,                n0,       0);
  STAGE(Bg, lds + 32768 + 8192,         n0 + 128, 0);
  STAGE(Bg, lds + 32768 + 16384,        n0,       64);
  STAGE(Bg, lds + 32768 + 16384 + 8192, n0 + 128, 64);
  asm volatile("s_waitcnt vmcnt(4)" ::: "memory");
  __builtin_amdgcn_s_barrier();
  __builtin_amdgcn_sched_barrier(0);

#pragma unroll 1
  for (int t = 0; t < NT; t++) {
    const int db = t & 1;
    short* Ab = lds + db*16384;
    short* Bb = lds + 32768 + db*16384;
    short* An = lds + (db ^ 1)*16384;
    const int kt = t*64;
    const bool stA = (t < NT - 1);
    const bool stB = (t < NT - 2);

    bf16x8 a[8], b[4][2];
    // ---- phase 0: kk=0 ----
#pragma unroll
    for (int mi = 0; mi < 8; mi++)
      a[mi] = *reinterpret_cast<const bf16x8*>(Ab + aoff0[mi]);
#pragma unroll
    for (int ni = 0; ni < 4; ni++) {
      b[ni][0] = *reinterpret_cast<const bf16x8*>(Bb + boff0[ni]);
      b[ni][1] = *reinterpret_cast<const bf16x8*>(Bb + (boff0[ni] ^ 32));
    }
    if (stA) {
      STAGE(Ag, An,        m0,       kt + 64);
      STAGE(Ag, An + 8192, m0 + 128, kt + 64);
    }
    PRE_MFMA();
#pragma unroll
    for (int mi = 0; mi < 8; mi++)
#pragma unroll
      for (int ni = 0; ni < 4; ni++)
        acc[mi][ni] = MFMA16(a[mi], b[ni][0], acc[mi][ni]);
    POST_MFMA();

    // ---- phase 1: kk=1 ----
#pragma unroll
    for (int mi = 0; mi < 8; mi++)
      a[mi] = *reinterpret_cast<const bf16x8*>(Ab + (aoff0[mi] ^ 32));
    if (stB) {
      STAGE(Bg, Bb,        n0,       kt + 128);
      STAGE(Bg, Bb + 8192, n0 + 128, kt + 128);
    }
    if (t >= NT - 2) asm volatile("s_waitcnt vmcnt(0)" ::: "memory");
    else             asm volatile("s_waitcnt vmcnt(4)" ::: "memory");
    PRE_MFMA();
#pragma unroll
    for (int mi = 0; mi < 8; mi++)
#pragma unroll
      for (int ni = 0; ni < 4; ni++)
        acc[mi][ni] = MFMA16(a[mi], b[ni][1], acc[mi][ni]);
    POST_MFMA();
  }
#undef STAGE
}

// ---------------- QKV projection + scatter (q,k -> [B,H,T,D]; v -> [B,H,D,T]) ----------------
__global__ __launch_bounds__(512, 2) void k_qkv(
    const unsigned short* __restrict__ xb,
    const unsigned short* __restrict__ wab,
    unsigned short* __restrict__ qr,
    unsigned short* __restrict__ kr,
    unsigned short* __restrict__ vt)
{
  __shared__ __align__(16) short lds[65536];
  f32x4 acc[8][4];
  int bid = blockIdx.x;                      // 768 blocks = 32 mt x 24 nt
  int swz = (bid & 7)*96 + (bid >> 3);       // bijective XCD swizzle (768 % 8 == 0)
  int m0 = (swz / 24)*256, n0 = (swz % 24)*256;
  gemm256_core(xb, wab, m0, n0, lds, acc);

  int tid = threadIdx.x, wid = tid >> 6, lane = tid & 63;
  int wm = wid >> 2, wn = wid & 3, r15 = lane & 15, hi4 = lane >> 4;
  int nw0 = n0 + wn*64;
  int which = nw0 >> 11;            // 0=q, 1=k, 2=v
  int h = (nw0 & 2047) >> 7;        // head (wave's 64 cols lie in one head)
#pragma unroll
  for (int mi = 0; mi < 8; mi++) {
    int m_base = m0 + wm*128 + mi*16 + hi4*4;
    int b = m_base >> 11;
    int t0 = m_base & (TT - 1);
#pragma unroll
    for (int ni = 0; ni < 4; ni++) {
      int d = (nw0 & 127) + ni*16 + r15;
      if (which == 2) {
        ushort4 pv;
        pv.x = f2bf(acc[mi][ni][0]); pv.y = f2bf(acc[mi][ni][1]);
        pv.z = f2bf(acc[mi][ni][2]); pv.w = f2bf(acc[mi][ni][3]);
        *reinterpret_cast<ushort4*>(vt + ((size_t)((b*NHEAD + h)*HD + d))*TT + t0) = pv;
      } else {
        unsigned short* dst = (which == 0) ? qr : kr;
        size_t base = ((size_t)(b*NHEAD + h)*TT + t0)*HD + d;
#pragma unroll
        for (int r = 0; r < 4; r++) dst[base + (size_t)r*HD] = f2bf(acc[mi][ni][r]);
      }
    }
  }
}

// ---------------- output projection ----------------
__global__ __launch_bounds__(512, 2) void k_proj(
    const unsigned short* __restrict__ yb,
    const unsigned short* __restrict__ wpb,
    float* __restrict__ out)
{
  __shared__ __align__(16) short lds[65536];
  f32x4 acc[8][4];
  int bid = blockIdx.x;                      // 256 blocks = 32 mt x 8 nt
  int swz = (bid & 7)*32 + (bid >> 3);
  int m0 = (swz / 8)*256, n0 = (swz % 8)*256;
  gemm256_core(yb, wpb, m0, n0, lds, acc);

  int tid = threadIdx.x, wid = tid >> 6, lane = tid & 63;
  int wm = wid >> 2, wn = wid & 3, r15 = lane & 15, hi4 = lane >> 4;
  int nw0 = n0 + wn*64;
#pragma unroll
  for (int mi = 0; mi < 8; mi++) {
    int m = m0 + wm*128 + mi*16 + hi4*4;
#pragma unroll
    for (int ni = 0; ni < 4; ni++) {
      int n = nw0 + ni*16 + r15;
#pragma unroll
      for (int r = 0; r < 4; r++)
        out[(size_t)(m + r)*CC + n] = acc[mi][ni][r];
    }
  }
}

// ---------------- in-place RoPE on q,k ----------------
__global__ void k_rope_apply(unsigned int* __restrict__ q32, unsigned int* __restrict__ k32,
                             const float* __restrict__ tab) {
  int i = blockIdx.x * 256 + threadIdx.x;   // over B*H*T*64
  int ii = i & 63;
  int t = (i >> 6) & (TT - 1);
  float c = tab[(t*64 + ii)*2], s = tab[(t*64 + ii)*2 + 1];
  unsigned qv = q32[i];
  float q1 = bf2f((unsigned short)qv), q2 = bf2f((unsigned short)(qv >> 16));
  unsigned short lo = f2bf(q1*c - q2*s), hi = f2bf(q1*s + q2*c);
  q32[i] = (unsigned)lo | ((unsigned)hi << 16);
  unsigned kv = k32[i];
  float k1 = bf2f((unsigned short)kv), k2 = bf2f((unsigned short)(kv >> 16));
  lo = f2bf(k1*c - k2*s); hi = f2bf(k1*s + k2*c);
  k32[i] = (unsigned)lo | ((unsigned)hi << 16);
}

// ---------------- causal flash attention, 2 q-subtiles/wave, async LDS staging ----------------
// grid: 512 blocks = 64 (b*h) * 8 pairs of 128-row q-blocks (qb, 15-qb)
//       -> uniform 34 KV tiles/block; 80KB LDS -> 2 blocks/CU.
// K/V double-buffered; staged via global_load_lds with INVERSE-swizzled per-lane
// global source + linear LDS dest (rule 21 involution; same XOR the reads use).
// No register staging -> ~45 fewer VGPR than round 6/7 (the spill source).
__global__ __launch_bounds__(256) void k_attn(
    const unsigned short* __restrict__ qr,
    const unsigned short* __restrict__ kr,
    const unsigned short* __restrict__ vt,
    unsigned short* __restrict__ yb)
{
  __shared__ __align__(16) short Ks[2][64*128];   // [buf][kv][d], chunk-XOR swizzled
  __shared__ __align__(16) short Vs[2][128*64];   // [buf][d][kv], chunk-XOR swizzled
  __shared__ short Pw[4*32*64];   // per-wave P (rows 0-15 sub0, 16-31 sub1), swizzled
  int bid = blockIdx.x;
  int bh = bid & 63, pr = bid >> 6;   // pr 0..7
  int tid = threadIdx.x, w = tid >> 6, lane = tid & 63;
  int r15 = lane & 15, hi4 = lane >> 4;
  const unsigned short* qg = qr + (size_t)bh*TT*HD;
  const unsigned short* kg = kr + (size_t)bh*TT*HD;
  const unsigned short* vg = vt + (size_t)bh*HD*TT;
  const f32x4 fz = {0.f,0.f,0.f,0.f};
  const float scale = 0.08838834764831845f; // 1/sqrt(128)
  int b = bh >> 4, h = bh & 15;

  // per-lane INVERSE-swizzled global source offsets (elements), fixed geometry:
  // K chunk i: LDS dest (w*4+i)*1024B + lane*16B -> row rK=(w*4+i)*4+(lane>>4),
  //            slot sK=lane&15, source chunk cK = sK ^ (rK&7)
  // V chunk i: LDS dest (w*4+i)*1024B + lane*16B -> row dV=(w*4+i)*8+(lane>>3),
  //            slot sV=lane&7,  source chunk cV = sV ^ (dV&7)
  int ksoff[4], vsoff[4];
#pragma unroll
  for (int i = 0; i < 4; i++) {
    int rK = (w*4 + i)*4 + (lane >> 4);
    int cK = (lane & 15) ^ (rK & 7);
    ksoff[i] = rK*HD + cK*8;
    int dV = (w*4 + i)*8 + (lane >> 3);
    int cV = (lane & 7) ^ (dV & 7);
    vsoff[i] = dV*TT + cV*8;
  }

#define STAGE_KV(BUF, KV0) do { \
    _Pragma("unroll") \
    for (int i_ = 0; i_ < 4; i_++) { \
      gl_lds16(kg + (size_t)(KV0)*HD + ksoff[i_], &Ks[BUF][(w*4 + i_)*512]); \
      gl_lds16(vg + (KV0) + vsoff[i_],            &Vs[BUF][(w*4 + i_)*512]); \
    } \
  } while(0)

#pragma unroll 1
  for (int ph = 0; ph < 2; ph++) {
    int qb = ph ? (15 - pr) : pr;
    int qlo0 = qb*128 + w*16, qlo1 = qlo0 + 64;
    bf16x8 qf0[4], qf1[4];
    {
      int q0 = qlo0 + r15, q1 = qlo1 + r15;
#pragma unroll
      for (int kk = 0; kk < 4; kk++) {
        qf0[kk] = *reinterpret_cast<const bf16x8*>(qg + (size_t)q0*HD + kk*32 + hi4*8);
        qf1[kk] = *reinterpret_cast<const bf16x8*>(qg + (size_t)q1*HD + kk*32 + hi4*8);
      }
    }
    f32x4 ao0[8], ao1[8];
#pragma unroll
    for (int i = 0; i < 8; i++) { ao0[i] = fz; ao1[i] = fz; }
    float mrow0[4], lsum0[4], mrow1[4], lsum1[4];
#pragma unroll
    for (int r = 0; r < 4; r++) {
      mrow0[r] = -3.0e38f; lsum0[r] = 0.f;
      mrow1[r] = -3.0e38f; lsum1[r] = 0.f;
    }
    int ntiles = 2*qb + 2;   // always even -> last tile reads buf 1; ph-prologue
                             // stages buf 0, so no cross-phase buffer conflict
    // prologue: stage tile 0 into buf 0
    STAGE_KV(0, 0);
    __syncthreads();         // drains vmcnt -> tile 0 visible to all waves
    int cur = 0;

#pragma unroll 1
    for (int it = 0; it < ntiles; ++it) {
      int kv0 = it*64;
      bool more = (it + 1 < ntiles);
      // ---- issue next tile's async staging into the other buffer ----
      if (more) STAGE_KV(cur ^ 1, kv0 + 64);
      const short* Kc = Ks[cur];
      const short* Vc = Vs[cur];
      // ---- QK^T both subtiles, shared K fragments ----
      f32x4 s0[4], s1[4];
      __builtin_amdgcn_s_setprio(1);
#pragma unroll
      for (int n = 0; n < 4; n++) {
        s0[n] = fz; s1[n] = fz;
#pragma unroll
        for (int kk = 0; kk < 4; kk++) {
          int kvr = n*16 + r15;
          int ch = (kk*4 + hi4) ^ (kvr & 7);
          bf16x8 kf = *reinterpret_cast<const bf16x8*>((const char*)Kc + kvr*256 + ch*16);
          s1[n] = MFMA16(qf1[kk], kf, s1[n]);
          s0[n] = MFMA16(qf0[kk], kf, s0[n]);
        }
      }
      __builtin_amdgcn_s_setprio(0);
      // ---- softmax sub0 ----
      {
        float p[4][4], rmax[4];
#pragma unroll
        for (int r = 0; r < 4; r++) {
          int qgi = qlo0 + hi4*4 + r;
          float mx = -3.0e38f;
#pragma unroll
          for (int n = 0; n < 4; n++) {
            int kvg = kv0 + n*16 + r15;
            float sv = s0[n][r]*scale;
            sv = (kvg <= qgi) ? sv : -3.0e38f;
            p[n][r] = sv;
            mx = fmaxf(mx, sv);
          }
          rmax[r] = mx;
        }
#pragma unroll
        for (int mm = 1; mm < 16; mm <<= 1)
#pragma unroll
          for (int r = 0; r < 4; r++) rmax[r] = fmaxf(rmax[r], __shfl_xor(rmax[r], mm));
        bool ng = (rmax[0] <= mrow0[0] + 8.f) && (rmax[1] <= mrow0[1] + 8.f)
               && (rmax[2] <= mrow0[2] + 8.f) && (rmax[3] <= mrow0[3] + 8.f);
        bool defer = __all(ng);
        float alpha[4];
#pragma unroll
        for (int r = 0; r < 4; r++) {
          if (defer) { alpha[r] = 1.f; }
          else {
            float mnew = fmaxf(mrow0[r], rmax[r]);
            alpha[r] = __expf(mrow0[r] - mnew);
            mrow0[r] = mnew;
          }
        }
        float rsum[4];
#pragma unroll
        for (int r = 0; r < 4; r++) {
          float sum = 0.f;
#pragma unroll
          for (int n = 0; n < 4; n++) {
            float pv = __expf(p[n][r] - mrow0[r]);
            p[n][r] = pv; sum += pv;
          }
          rsum[r] = sum;
        }
#pragma unroll
        for (int mm = 1; mm < 16; mm <<= 1)
#pragma unroll
          for (int r = 0; r < 4; r++) rsum[r] += __shfl_xor(rsum[r], mm);
#pragma unroll
        for (int r = 0; r < 4; r++) lsum0[r] = lsum0[r]*alpha[r] + rsum[r];
        if (!defer) {
#pragma unroll
          for (int i = 0; i < 8; i++)
#pragma unroll
            for (int r = 0; r < 4; r++) ao0[i][r] *= alpha[r];
        }
#pragma unroll
        for (int r = 0; r < 4; r++) {
          int prow = hi4*4 + r;
#pragma unroll
          for (int n = 0; n < 4; n++) {
            int col = n*16 + r15;
            Pw[w*2048 + prow*64 + (col ^ ((prow & 7) << 3))] = (short)f2bf(p[n][r]);
          }
        }
      }
      // ---- softmax sub1 ----
      {
        float p[4][4], rmax[4];
#pragma unroll
        for (int r = 0; r < 4; r++) {
          int qgi = qlo1 + hi4*4 + r;
          float mx = -3.0e38f;
#pragma unroll
          for (int n = 0; n < 4; n++) {
            int kvg = kv0 + n*16 + r15;
            float sv = s1[n][r]*scale;
            sv = (kvg <= qgi) ? sv : -3.0e38f;
            p[n][r] = sv;
            mx = fmaxf(mx, sv);
          }
          rmax[r] = mx;
        }
#pragma unroll
        for (int mm = 1; mm < 16; mm <<= 1)
#pragma unroll
          for (int r = 0; r < 4; r++) rmax[r] = fmaxf(rmax[r], __shfl_xor(rmax[r], mm));
        bool ng = (rmax[0] <= mrow1[0] + 8.f) && (rmax[1] <= mrow1[1] + 8.f)
               && (rmax[2] <= mrow1[2] + 8.f) && (rmax[3] <= mrow1[3] + 8.f);
        bool defer = __all(ng);
        float alpha[4];
#pragma unroll
        for (int r = 0; r < 4; r++) {
          if (defer) { alpha[r] = 1.f; }
          else {
            float mnew = fmaxf(mrow1[r], rmax[r]);
            alpha[r] = __expf(mrow1[r] - mnew);
            mrow1[r] = mnew;
          }
        }
        float rsum[4];
#pragma unroll
        for (int r = 0; r < 4; r++) {
          float sum = 0.f;
#pragma unroll
          for (int n = 0; n < 4; n++) {
            float pv = __expf(p[n][r] - mrow1[r]);
            p[n][r] = pv; sum += pv;
          }
          rsum[r] = sum;
        }
#pragma unroll
        for (int mm = 1; mm < 16; mm <<= 1)
#pragma unroll
          for (int r = 0; r < 4; r++) rsum[r] += __shfl_xor(rsum[r], mm);
#pragma unroll
        for (int r = 0; r < 4; r++) lsum1[r] = lsum1[r]*alpha[r] + rsum[r];
        if (!defer) {
#pragma unroll
          for (int i = 0; i < 8; i++)
#pragma unroll
            for (int r = 0; r < 4; r++) ao1[i][r] *= alpha[r];
        }
#pragma unroll
        for (int r = 0; r < 4; r++) {
          int prow = 16 + hi4*4 + r;
#pragma unroll
          for (int n = 0; n < 4; n++) {
            int col = n*16 + r15;
            Pw[w*2048 + prow*64 + (col ^ ((prow & 7) << 3))] = (short)f2bf(p[n][r]);
          }
        }
      }
      // ---- PV both subtiles, shared V fragments ----
      __builtin_amdgcn_s_setprio(1);
#pragma unroll
      for (int kk = 0; kk < 2; kk++) {
        int ch = (kk*4 + hi4) ^ (r15 & 7);
        bf16x8 pa0 = *reinterpret_cast<const bf16x8*>((char*)Pw + w*4096 + r15*128 + ch*16);
        bf16x8 pa1 = *reinterpret_cast<const bf16x8*>((char*)Pw + w*4096 + (16 + r15)*128 + ch*16);
#pragma unroll
        for (int ds_ = 0; ds_ < 8; ds_++) {
          int d = ds_*16 + r15;
          int vch = (kk*4 + hi4) ^ (d & 7);
          bf16x8 vf = *reinterpret_cast<const bf16x8*>((const char*)Vc + d*128 + vch*16);
          ao1[ds_] = MFMA16(pa1, vf, ao1[ds_]);
          ao0[ds_] = MFMA16(pa0, vf, ao0[ds_]);
        }
      }
      __builtin_amdgcn_s_setprio(0);
      // ---- publish staged tile (barrier drains vmcnt+lgkmcnt), swap ----
      __syncthreads();
      cur ^= 1;
    }
    // ---- epilogue both subtiles ----
#pragma unroll
    for (int r = 0; r < 4; r++) {
      int t0 = qlo0 + hi4*4 + r;
      int t1 = qlo1 + hi4*4 + r;
      float inv0 = 1.f / lsum0[r];
      float inv1 = 1.f / lsum1[r];
      size_t base0 = ((size_t)b*TT + t0)*CC + h*HD + r15;
      size_t base1 = ((size_t)b*TT + t1)*CC + h*HD + r15;
#pragma unroll
      for (int ds_ = 0; ds_ < 8; ds_++) {
        yb[base0 + ds_*16] = f2bf(ao0[ds_][r] * inv0);
        yb[base1 + ds_*16] = f2bf(ao1[ds_][r] * inv1);
      }
    }
  }
#undef STAGE_KV
}

extern "C" void kernel_launch(void* const* d_in, const int* in_sizes, int n_in,
                              void* d_out, int out_size, void* d_ws, size_t ws_size,
                              hipStream_t stream) {
  const float* x  = (const float*)d_in[0];
  const float* wa = (const float*)d_in[1];
  const float* wp = (const float*)d_in[2];
  float* out = (float*)d_out;
  char* ws = (char*)d_ws;
  size_t off = 0;
  unsigned short* xb  = (unsigned short*)(ws + off); off += (size_t)MTOT*CC*2;
  unsigned short* wab = (unsigned short*)(ws + off); off += (size_t)3*CC*CC*2;
  unsigned short* wpb = (unsigned short*)(ws + off); off += (size_t)CC*CC*2;
  unsigned short* qr  = (unsigned short*)(ws + off); off += (size_t)MTOT*CC*2;
  unsigned short* kr  = (unsigned short*)(ws + off); off += (size_t)MTOT*CC*2;
  unsigned short* vt  = (unsigned short*)(ws + off); off += (size_t)MTOT*CC*2;
  unsigned short* yb  = (unsigned short*)(ws + off); off += (size_t)MTOT*CC*2;
  float* tab          = (float*)(ws + off);          off += (size_t)TT*64*2*4;

  k_f2b<<<dim3(16384), dim3(256), 0, stream>>>(x,  xb,  MTOT*CC/4);
  k_f2b<<<dim3(12288), dim3(256), 0, stream>>>(wa, wab, 3*CC*CC/4);
  k_f2b<<<dim3(4096),  dim3(256), 0, stream>>>(wp, wpb, CC*CC/4);
  k_rope_tab<<<dim3(TT), dim3(64), 0, stream>>>(tab);
  k_qkv<<<dim3(768), dim3(512), 0, stream>>>(xb, wab, qr, kr, vt);
  k_rope_apply<<<dim3(32768), dim3(256), 0, stream>>>((unsigned int*)qr, (unsigned int*)kr, tab);
  k_attn<<<dim3(512), dim3(256), 0, stream>>>(qr, kr, vt, yb);
  k_proj<<<dim3(256), dim3(512), 0, stream>>>(yb, wpb, out);
}